// Round 4
// baseline (675.553 us; speedup 1.0000x reference)
//
#include <hip/hip_runtime.h>

typedef __bf16 bf16x8 __attribute__((ext_vector_type(8)));
typedef float f32x4 __attribute__((ext_vector_type(4)));
typedef unsigned short us8 __attribute__((ext_vector_type(8)));

#define B_ 64
#define T_ 1024
#define N_ 1024

__device__ __forceinline__ unsigned short f2bf(float f) {
  unsigned int u = __float_as_uint(f);
  u += 0x7fffu + ((u >> 16) & 1u);   // round-to-nearest-even
  return (unsigned short)(u >> 16);
}

__device__ __forceinline__ float fast_tanh(float x) {
  float xc = fminf(fmaxf(x, -15.f), 15.f);
  float e = __expf(2.f * xc);
  return (e - 1.f) / (e + 1.f);
}

// ============ swizzled fragment layout ============
// tile(b, tb, kb): 16 rows (tb*16..+16) x 32 k (kb*32..+32) stored as 1KB:
//   short[tau*512 + l*8 + j] = M[tb*16 + (l&15)][kb*32 + (l>>4)*8 + j]
// This is exactly the mfma_f32_16x16x32_bf16 A/B lane layout -> a wave's
// global_load_dwordx4 at base+lane*16 IS the fragment load. No LDS needed.

// ---- Kernel 1: swizzle W_h -> fragment order; zero scores & c_t ----
__global__ __launch_bounds__(256) void k_swz_w(const float* __restrict__ W_h,
                                               unsigned short* __restrict__ wsw,
                                               float* __restrict__ scores,
                                               float* __restrict__ ct) {
  const int tau = blockIdx.x * 4 + (threadIdx.x >> 6);   // 0..2047
  const int l = threadIdx.x & 63;
  const int mb = tau >> 5, kb = tau & 31;
  const int row = mb * 16 + (l & 15);
  const int kof = kb * 32 + (l >> 4) * 8;
  const float* src = W_h + (size_t)row * N_ + kof;
  float4 x = *(const float4*)src;
  float4 y = *(const float4*)(src + 4);
  us8 o;
  o[0] = f2bf(x.x); o[1] = f2bf(x.y); o[2] = f2bf(x.z); o[3] = f2bf(x.w);
  o[4] = f2bf(y.x); o[5] = f2bf(y.y); o[6] = f2bf(y.z); o[7] = f2bf(y.w);
  *(us8*)(wsw + (size_t)tau * 512 + l * 8) = o;
  const int gid = blockIdx.x * 256 + threadIdx.x;        // 131072 threads
  if (gid < B_ * T_) scores[gid] = 0.f;
  if (gid < B_ * N_) ct[gid] = 0.f;
}

// ---- Kernel 1b: swizzle h -> fragment order ----
__global__ __launch_bounds__(256) void k_swz_h(const float* __restrict__ h,
                                               unsigned short* __restrict__ hs) {
  const int tau = blockIdx.x * 4 + (threadIdx.x >> 6);   // 0..131071
  const int l = threadIdx.x & 63;
  const int b = tau >> 11;
  const int tb = (tau >> 5) & 63;
  const int kb = tau & 31;
  const int row = tb * 16 + (l & 15);
  const int kof = kb * 32 + (l >> 4) * 8;
  const float* src = h + ((size_t)(b << 10) + row) * N_ + kof;
  float4 x = *(const float4*)src;
  float4 y = *(const float4*)(src + 4);
  us8 o;
  o[0] = f2bf(x.x); o[1] = f2bf(x.y); o[2] = f2bf(x.z); o[3] = f2bf(x.w);
  o[4] = f2bf(y.x); o[5] = f2bf(y.y); o[6] = f2bf(y.z); o[7] = f2bf(y.w);
  *(us8*)(hs + (size_t)tau * 512 + l * 8) = o;
}

// ---- Kernel 2: dec_fea[b,m] = s_t_hat[b,:] . dec_W[m,:] + dec_b[m] ----
__global__ __launch_bounds__(256) void k_decfea2(const float* __restrict__ s_t_hat,
                                                 const float* __restrict__ dec_W,
                                                 const float* __restrict__ dec_b,
                                                 float* __restrict__ dec_fea) {
  const int m0 = blockIdx.x * 64;
  const int bg0 = blockIdx.y * 8;
  __shared__ float sh[8][N_];
  __shared__ float red[4][64][8];
  const int tid = threadIdx.x;
  for (int idx = tid; idx < 8 * N_; idx += 256) {
    int bb = idx >> 10, k = idx & (N_ - 1);
    sh[bb][k] = s_t_hat[(size_t)(bg0 + bb) * N_ + k];
  }
  __syncthreads();
  const int tm = tid >> 2;
  const int seg = tid & 3;
  const float* w = dec_W + (size_t)(m0 + tm) * N_;
  float acc[8];
#pragma unroll
  for (int bb = 0; bb < 8; bb++) acc[bb] = 0.f;
  for (int i = 0; i < 64; i++) {
    int k = seg * 4 + i * 16;
    float4 wv = *(const float4*)(w + k);
#pragma unroll
    for (int bb = 0; bb < 8; bb++)
      acc[bb] += sh[bb][k] * wv.x + sh[bb][k + 1] * wv.y + sh[bb][k + 2] * wv.z + sh[bb][k + 3] * wv.w;
  }
#pragma unroll
  for (int bb = 0; bb < 8; bb++) red[seg][tm][bb] = acc[bb];
  __syncthreads();
  int om = tid & 63, ob = tid >> 6;
#pragma unroll
  for (int p = 0; p < 2; p++) {
    int obb = ob + p * 4;
    float s = red[0][om][obb] + red[1][om][obb] + red[2][om][obb] + red[3][om][obb] + dec_b[m0 + om];
    dec_fea[(size_t)(bg0 + obb) * N_ + m0 + om] = s;
  }
}

// ---- Kernel 3 (main): fused scores; NO LDS, NO barriers in K-loop.
//      Fragments loaded directly from pre-swizzled hs/wsw; ping-pong prefetch. ----
__global__ __launch_bounds__(256) void k_score3(
    const unsigned short* __restrict__ hs, const unsigned short* __restrict__ wsw,
    const float* __restrict__ dec_fea, const float* __restrict__ coverage,
    const float* __restrict__ W_c, const float* __restrict__ v,
    float* __restrict__ scores) {
  const int tid = threadIdx.x;
  // XCD swizzle: bid&7 = XCD; each XCD owns 64 (t,b) tiles x 8 m-tiles, m fastest.
  const int bid = blockIdx.x;
  const int xcd = bid & 7;
  const int local = bid >> 3;
  const int mi = local & 7;
  const int tb = xcd * 64 + (local >> 3);
  const int b = tb >> 3;
  const int t8 = tb & 7;              // 128-row t-tile index
  const int m0 = mi * 128;
  const int t0 = t8 * 128;

  const int wave = tid >> 6, lane = tid & 63;
  const int wr = wave >> 1, wc = wave & 1;
  const int lm = lane & 15, lq = lane >> 4;

  f32x4 acc[4][4];
#pragma unroll
  for (int i = 0; i < 4; i++)
#pragma unroll
    for (int j = 0; j < 4; j++) acc[i][j] = (f32x4){0.f, 0.f, 0.f, 0.f};

  // base pointers to this wave's first fragment tiles (units: shorts)
  const unsigned short* pA = hs + (((size_t)b * 64 + t8 * 8 + wr * 4) << 5 << 9) + lane * 8;
  const unsigned short* pB = wsw + (((size_t)(mi * 8 + wc * 4)) << 5 << 9) + lane * 8;
  // fragment (i, kb) lives at offset ((i<<5)+kb)<<9 shorts from pA/pB

  us8 aA[4], bA[4], aB[4], bB[4];
#pragma unroll
  for (int i = 0; i < 4; i++) {
    aA[i] = *(const us8*)(pA + ((i << 5) << 9));
    bA[i] = *(const us8*)(pB + ((i << 5) << 9));
  }
  for (int kb = 0; kb < 32; kb += 2) {
#pragma unroll
    for (int i = 0; i < 4; i++) {
      aB[i] = *(const us8*)(pA + (((i << 5) + kb + 1) << 9));
      bB[i] = *(const us8*)(pB + (((i << 5) + kb + 1) << 9));
    }
#pragma unroll
    for (int i = 0; i < 4; i++)
#pragma unroll
      for (int j = 0; j < 4; j++)
        acc[i][j] = __builtin_amdgcn_mfma_f32_16x16x32_bf16(
            __builtin_bit_cast(bf16x8, aA[i]), __builtin_bit_cast(bf16x8, bA[j]),
            acc[i][j], 0, 0, 0);
    if (kb + 2 < 32) {
#pragma unroll
      for (int i = 0; i < 4; i++) {
        aA[i] = *(const us8*)(pA + (((i << 5) + kb + 2) << 9));
        bA[i] = *(const us8*)(pB + (((i << 5) + kb + 2) << 9));
      }
    }
#pragma unroll
    for (int i = 0; i < 4; i++)
#pragma unroll
      for (int j = 0; j < 4; j++)
        acc[i][j] = __builtin_amdgcn_mfma_f32_16x16x32_bf16(
            __builtin_bit_cast(bf16x8, aB[i]), __builtin_bit_cast(bf16x8, bB[j]),
            acc[i][j], 0, 0, 0);
  }

  // epilogue: scores[b,t] += sum_m tanh(S + dec_fea[m] + cov[t]*W_c[m]) * v[m]
  float dfv[4], wcv[4], vv[4];
#pragma unroll
  for (int j = 0; j < 4; j++) {
    int m = m0 + wc * 64 + j * 16 + lm;   // D col = lane&15
    dfv[j] = dec_fea[b * N_ + m];
    wcv[j] = W_c[m];
    vv[j] = v[m];
  }
#pragma unroll
  for (int i = 0; i < 4; i++) {
#pragma unroll
    for (int r = 0; r < 4; r++) {
      int t = t0 + wr * 64 + i * 16 + lq * 4 + r;  // D row = quad*4 + reg
      float cv = coverage[b * T_ + t];
      float s = 0.f;
#pragma unroll
      for (int j = 0; j < 4; j++) {
        float x = acc[i][j][r] + dfv[j] + cv * wcv[j];
        s += fast_tanh(x) * vv[j];
      }
      s += __shfl_xor(s, 1);
      s += __shfl_xor(s, 2);
      s += __shfl_xor(s, 4);
      s += __shfl_xor(s, 8);
      if (lm == 0) atomicAdd(&scores[b * T_ + t], s);
    }
  }
}

// ---- Kernel 3 (fallback, small ws): fp32 h staging via LDS (R1-proven) ----
__global__ __launch_bounds__(256) void k_score_fb(
    const float* __restrict__ h, const unsigned short* __restrict__ whb,
    const float* __restrict__ dec_fea, const float* __restrict__ coverage,
    const float* __restrict__ W_c, const float* __restrict__ v,
    float* __restrict__ scores) {
  __shared__ __align__(16) unsigned short lsA[128 * 40];
  __shared__ __align__(16) unsigned short lsB[128 * 40];
  const int tid = threadIdx.x;
  const int b = blockIdx.z;
  const int t0 = blockIdx.y * 128;
  const int m0 = blockIdx.x * 128;
  const int wave = tid >> 6, lane = tid & 63;
  const int wr = wave >> 1, wc = wave & 1;
  const int lm = lane & 15, lq = lane >> 4;
  f32x4 acc[4][4];
#pragma unroll
  for (int i = 0; i < 4; i++)
#pragma unroll
    for (int j = 0; j < 4; j++) acc[i][j] = (f32x4){0.f, 0.f, 0.f, 0.f};
  const float* hA = h + ((size_t)b * T_ + t0) * N_;
  const unsigned short* wB = whb + (size_t)m0 * N_;
  for (int k0 = 0; k0 < N_; k0 += 32) {
    __syncthreads();
    for (int s = tid; s < 512; s += 256) {
      int row = s >> 2, kc = (s & 3) * 8;
      const float* src = hA + (size_t)row * N_ + k0 + kc;
      float4 x = *(const float4*)src;
      float4 y = *(const float4*)(src + 4);
      unsigned short* d = &lsA[row * 40 + kc];
      d[0] = f2bf(x.x); d[1] = f2bf(x.y); d[2] = f2bf(x.z); d[3] = f2bf(x.w);
      d[4] = f2bf(y.x); d[5] = f2bf(y.y); d[6] = f2bf(y.z); d[7] = f2bf(y.w);
    }
    for (int s = tid; s < 512; s += 256) {
      int row = s >> 2, kc = (s & 3) * 8;
      us8 x = *(const us8*)(wB + (size_t)row * N_ + k0 + kc);
      *(us8*)&lsB[row * 40 + kc] = x;
    }
    __syncthreads();
    bf16x8 af[4], bfr[4];
#pragma unroll
    for (int i = 0; i < 4; i++)
      af[i] = __builtin_bit_cast(bf16x8, *(const us8*)&lsA[(wr * 64 + i * 16 + lm) * 40 + lq * 8]);
#pragma unroll
    for (int j = 0; j < 4; j++)
      bfr[j] = __builtin_bit_cast(bf16x8, *(const us8*)&lsB[(wc * 64 + j * 16 + lm) * 40 + lq * 8]);
#pragma unroll
    for (int i = 0; i < 4; i++)
#pragma unroll
      for (int j = 0; j < 4; j++)
        acc[i][j] = __builtin_amdgcn_mfma_f32_16x16x32_bf16(af[i], bfr[j], acc[i][j], 0, 0, 0);
  }
  float dfv[4], wcv[4], vv[4];
#pragma unroll
  for (int j = 0; j < 4; j++) {
    int m = m0 + wc * 64 + j * 16 + lm;
    dfv[j] = dec_fea[b * N_ + m];
    wcv[j] = W_c[m];
    vv[j] = v[m];
  }
#pragma unroll
  for (int i = 0; i < 4; i++) {
#pragma unroll
    for (int r = 0; r < 4; r++) {
      int t = t0 + wr * 64 + i * 16 + lq * 4 + r;
      float cv = coverage[b * T_ + t];
      float s = 0.f;
#pragma unroll
      for (int j = 0; j < 4; j++) {
        float x = acc[i][j][r] + dfv[j] + cv * wcv[j];
        s += fast_tanh(x) * vv[j];
      }
      s += __shfl_xor(s, 1);
      s += __shfl_xor(s, 2);
      s += __shfl_xor(s, 4);
      s += __shfl_xor(s, 8);
      if (lm == 0) atomicAdd(&scores[b * T_ + t], s);
    }
  }
}

// ---- Kernel 1 (fallback): row-major W_h -> bf16; zero scores & c_t ----
__global__ __launch_bounds__(256) void k_cvt_wh(const float* __restrict__ W_h,
                                                unsigned short* __restrict__ whb,
                                                float* __restrict__ scores,
                                                float* __restrict__ ct) {
  int base = blockIdx.x * 256 + threadIdx.x;
  size_t i = (size_t)base * 4;
  float4 x = *(const float4*)(W_h + i);
  ushort4 o;
  o.x = f2bf(x.x); o.y = f2bf(x.y); o.z = f2bf(x.z); o.w = f2bf(x.w);
  *(ushort4*)(whb + i) = o;
  if (base < B_ * T_) scores[base] = 0.f;
  if (base < B_ * N_) ct[base] = 0.f;
}

// ---- Kernel 4: softmax over t, mask, renormalize; write attn + coverage_new ----
__global__ __launch_bounds__(256) void k_softmax(const float* __restrict__ scores,
                                                 const float* __restrict__ mask,
                                                 const float* __restrict__ coverage,
                                                 float* __restrict__ attn_out,
                                                 float* __restrict__ cov_out) {
  const int b = blockIdx.x, tid = threadIdx.x;
  const int wave = tid >> 6, lane = tid & 63;
  const float* s = scores + b * T_;
  float vals[4];
  float lmax = -1e30f;
#pragma unroll
  for (int i = 0; i < 4; i++) {
    vals[i] = s[i * 256 + tid];
    lmax = fmaxf(lmax, vals[i]);
  }
#pragma unroll
  for (int off = 1; off < 64; off <<= 1) lmax = fmaxf(lmax, __shfl_xor(lmax, off));
  __shared__ float rmax[4], rsum[4];
  if (lane == 0) rmax[wave] = lmax;
  __syncthreads();
  float bmax = fmaxf(fmaxf(rmax[0], rmax[1]), fmaxf(rmax[2], rmax[3]));
  float w[4];
  float lsum = 0.f;
#pragma unroll
  for (int i = 0; i < 4; i++) {
    float e = __expf(vals[i] - bmax) * mask[b * T_ + i * 256 + tid];
    w[i] = e;
    lsum += e;
  }
#pragma unroll
  for (int off = 1; off < 64; off <<= 1) lsum += __shfl_xor(lsum, off);
  if (lane == 0) rsum[wave] = lsum;
  __syncthreads();
  float inv = 1.f / (rsum[0] + rsum[1] + rsum[2] + rsum[3]);
#pragma unroll
  for (int i = 0; i < 4; i++) {
    int t = i * 256 + tid;
    float a = w[i] * inv;
    attn_out[b * T_ + t] = a;
    cov_out[b * T_ + t] = coverage[b * T_ + t] + a;
  }
}

// ---- Kernel 5 (main): c_t from swizzled hs; coalesced 16B loads, shfl-reduce ----
__global__ __launch_bounds__(256) void k_ctx3(const unsigned short* __restrict__ hs,
                                              const float* __restrict__ attn,
                                              float* __restrict__ c_t) {
  const int b = blockIdx.y;
  const int z = blockIdx.z;                              // tb half: 0 or 1
  const int kb = blockIdx.x * 4 + (threadIdx.x >> 6);    // 0..31
  const int l = threadIdx.x & 63;
  __shared__ float la[T_];
  for (int i = threadIdx.x; i < T_; i += 256) la[i] = attn[b * T_ + i];
  __syncthreads();
  const unsigned short* p = hs + (((size_t)b * 64 + z * 32) << 5 << 9) + ((size_t)kb << 9) + l * 8;
  float acc[8] = {0.f, 0.f, 0.f, 0.f, 0.f, 0.f, 0.f, 0.f};
  const int trow = l & 15;
#pragma unroll 4
  for (int tb = 0; tb < 32; tb++) {
    us8 u = *(const us8*)(p + ((size_t)tb << 5 << 9));
    float a = la[(z * 32 + tb) * 16 + trow];
#pragma unroll
    for (int j = 0; j < 8; j++) acc[j] += a * __uint_as_float((unsigned)u[j] << 16);
  }
#pragma unroll
  for (int j = 0; j < 8; j++) {
    acc[j] += __shfl_xor(acc[j], 1);
    acc[j] += __shfl_xor(acc[j], 2);
    acc[j] += __shfl_xor(acc[j], 4);
    acc[j] += __shfl_xor(acc[j], 8);
  }
  if (trow == 0) {
    int n0 = kb * 32 + (l >> 4) * 8;
#pragma unroll
    for (int j = 0; j < 8; j++) atomicAdd(&c_t[b * N_ + n0 + j], acc[j]);
  }
}

// ---- Kernel 5 (fallback): fp32 h ----
__global__ __launch_bounds__(256) void k_ctx_fb(const float* __restrict__ h,
                                                const float* __restrict__ attn,
                                                float* __restrict__ c_t) {
  const int b = blockIdx.y;
  const int n = blockIdx.x * 256 + threadIdx.x;
  __shared__ float la[T_];
  for (int i = threadIdx.x; i < T_; i += 256) la[i] = attn[b * T_ + i];
  __syncthreads();
  const float* hb = h + (size_t)b * T_ * N_ + n;
  float acc = 0.f;
#pragma unroll 8
  for (int t = 0; t < T_; t++) acc += la[t] * hb[(size_t)t * N_];
  c_t[b * N_ + n] = acc;
}

extern "C" void kernel_launch(void* const* d_in, const int* in_sizes, int n_in,
                              void* d_out, int out_size, void* d_ws, size_t ws_size,
                              hipStream_t stream) {
  const float* s_t_hat  = (const float*)d_in[0];
  const float* h        = (const float*)d_in[1];
  const float* mask     = (const float*)d_in[2];
  const float* coverage = (const float*)d_in[3];
  const float* W_h      = (const float*)d_in[4];
  const float* W_c      = (const float*)d_in[5];
  const float* dec_W    = (const float*)d_in[6];
  const float* dec_b    = (const float*)d_in[7];
  const float* v        = (const float*)d_in[8];

  float* out = (float*)d_out;
  float* out_ct   = out;                 // [B,N]
  float* out_attn = out + B_ * T_;       // [B,T]
  float* out_cov  = out + 2 * B_ * T_;   // [B,T]

  const size_t hbf_bytes = (size_t)B_ * T_ * N_ * 2;   // 128 MB
  const size_t whb_bytes = (size_t)N_ * N_ * 2;        // 2 MB
  const size_t df_bytes  = (size_t)B_ * N_ * 4;        // 256 KB
  const size_t sc_bytes  = (size_t)B_ * T_ * 4;        // 256 KB
  const bool big = ws_size >= hbf_bytes + whb_bytes + df_bytes + sc_bytes;

  char* ws = (char*)d_ws;
  if (big) {
    unsigned short* hs  = (unsigned short*)ws;
    unsigned short* wsw = (unsigned short*)(ws + hbf_bytes);
    float* dec_fea = (float*)(ws + hbf_bytes + whb_bytes);
    float* scores  = (float*)(ws + hbf_bytes + whb_bytes + df_bytes);

    k_swz_w<<<dim3(512), 256, 0, stream>>>(W_h, wsw, scores, out_ct);
    k_swz_h<<<dim3(32768), 256, 0, stream>>>(h, hs);
    k_decfea2<<<dim3(16, 8), 256, 0, stream>>>(s_t_hat, dec_W, dec_b, dec_fea);
    k_score3<<<dim3(4096), 256, 0, stream>>>(hs, wsw, dec_fea, coverage, W_c, v, scores);
    k_softmax<<<dim3(B_), 256, 0, stream>>>(scores, mask, coverage, out_attn, out_cov);
    k_ctx3<<<dim3(8, B_, 2), 256, 0, stream>>>(hs, out_attn, out_ct);
  } else {
    unsigned short* whb = (unsigned short*)ws;
    float* dec_fea = (float*)(ws + whb_bytes);
    float* scores  = (float*)(ws + whb_bytes + df_bytes);

    k_cvt_wh<<<dim3(N_ * N_ / 1024), 256, 0, stream>>>(W_h, whb, scores, out_ct);
    k_decfea2<<<dim3(16, 8), 256, 0, stream>>>(s_t_hat, dec_W, dec_b, dec_fea);
    k_score_fb<<<dim3(N_ / 128, T_ / 128, B_), 256, 0, stream>>>(h, whb, dec_fea, coverage, W_c, v, scores);
    k_softmax<<<dim3(B_), 256, 0, stream>>>(scores, mask, coverage, out_attn, out_cov);
    k_ctx_fb<<<dim3(4, B_), 256, 0, stream>>>(h, out_attn, out_ct);
  }
}